// Round 3
// baseline (457.938 us; speedup 1.0000x reference)
//
#include <hip/hip_runtime.h>
#include <cstddef>
#include <type_traits>

// MediumLSTM v6.1: row-split over 8 waves (512 thr/block), constant total VALU issue.
// Identical to v6 except bar_lds() uses __builtin_amdgcn_s_barrier() (convergent,
// compiler-visible) instead of a raw asm s_barrier. v6 bench was an infra failure,
// not a kernel verdict; this resubmission hardens the only compiler-risky construct.
//
// v5 calibration: VALUBusy is real issue, dominated by v_exp/v_rcp at ~16cyc/wave64
// op; ~50% VALU-busy at 2 waves/SIMD. v6 splits each v5 wave's elementwise in half
// across a wave PAIR (w, w+4): both duplicate the (cheap, 7%-util) MFMAs, wave w
// handles row-slot rr=0, wave w+4 handles rr=1. Per-wave trans issue halves, wave
// count doubles (4096 waves, 16/CU, 4/SIMD) -> wall compresses toward the VALU
// issue floor (~3000 cyc/SIMD/step ~ 82us/dispatch).
// Barrier: s_waitcnt lgkmcnt(0) + s_barrier only (no vmcnt drain) so the x
// prefetch stays in flight across steps (register-consumed, HW-enforced at use).
//
// Work map per step (wid8 = tid>>6, w = wid8&3, rsel = wid8>>2):
//   L1: all waves, tau-pair w (10 MFMA), elementwise rr=rsel       (1 cell/lane)
//   L2: waves w<2 (wid8 0,1,4,5), unit-group w, rr=rsel            (1 cell/lane)
//   L3: waves wid8==2,3 only, rp=wid8-2                            (1 cell/lane)
// Parity map (P = t&1), unchanged:
//   L1: reads h1s[1-P], xs[P];  writes h1s[P]    (h1[t])
//   L2: reads h1s[1-P], h2s[P]; writes h2s[1-P]  (h2[t-1])
//   L3: reads h2s[P], h3s[1-P]; writes h3s[P]    (h3[t-2])
//   FC: h3[63] lands in h3s[1] (iter 65).

typedef _Float16 h8_t  __attribute__((ext_vector_type(8)));
typedef _Float16 h4_t  __attribute__((ext_vector_type(4)));
typedef __fp16   p2_t  __attribute__((ext_vector_type(2)));
typedef float    f4_t  __attribute__((ext_vector_type(4)));

#define T_LEN 64
#define D_IN  128

__device__ __forceinline__ float sig_(float x)  { return 1.0f / (1.0f + __expf(-x)); }
__device__ __forceinline__ float tanh_(float x) { float e = __expf(2.0f * x); return 1.0f - 2.0f / (e + 1.0f); }

__device__ __forceinline__ h8_t zero8h() {
    h8_t r = { (_Float16)0.f,(_Float16)0.f,(_Float16)0.f,(_Float16)0.f,
               (_Float16)0.f,(_Float16)0.f,(_Float16)0.f,(_Float16)0.f };
    return r;
}
__device__ __forceinline__ h8_t cvt8(f4_t lo, f4_t hi) {
    union { h8_t v8; p2_t v2[4]; } u;
    u.v2[0] = __builtin_amdgcn_cvt_pkrtz(lo[0], lo[1]);
    u.v2[1] = __builtin_amdgcn_cvt_pkrtz(lo[2], lo[3]);
    u.v2[2] = __builtin_amdgcn_cvt_pkrtz(hi[0], hi[1]);
    u.v2[3] = __builtin_amdgcn_cvt_pkrtz(hi[2], hi[3]);
    return u.v8;
}
__device__ __forceinline__ h4_t cvt4(f4_t v) {
    union { h4_t v4; p2_t v2[2]; } u;
    u.v2[0] = __builtin_amdgcn_cvt_pkrtz(v[0], v[1]);
    u.v2[1] = __builtin_amdgcn_cvt_pkrtz(v[2], v[3]);
    return u.v4;
}
__device__ __forceinline__ h8_t load8f_h(const float* __restrict__ p) {
    f4_t lo = *(const f4_t*)p, hi = *(const f4_t*)(p + 4);
    return cvt8(lo, hi);
}

// lgkm-only barrier: LDS writes committed (lgkmcnt=0) before the convergent
// barrier; x-prefetch (vmcnt) stays in flight, HW-enforced at register use.
__device__ __forceinline__ void bar_lds() {
    asm volatile("s_waitcnt lgkmcnt(0)" ::: "memory");
    __builtin_amdgcn_s_barrier();
}

__global__ __launch_bounds__(512, 4)
void lstm_one(const float* __restrict__ x,
              const float* __restrict__ w_ih1, const float* __restrict__ w_hh1,
              const float* __restrict__ b_ih1, const float* __restrict__ b_hh1,
              const float* __restrict__ w_ih2, const float* __restrict__ w_hh2,
              const float* __restrict__ b_ih2, const float* __restrict__ b_hh2,
              const float* __restrict__ w_ih3, const float* __restrict__ w_hh3,
              const float* __restrict__ b_ih3, const float* __restrict__ b_hh3,
              const float* __restrict__ fc_w, const float* __restrict__ fc_b,
              float* __restrict__ out)
{
    __shared__ __align__(16) _Float16 h1s[2][16][40];
    __shared__ __align__(16) _Float16 h2s[2][16][24];
    __shared__ __align__(16) _Float16 h3s[2][16][8];
    __shared__ __align__(16) _Float16 xs[2][16 * 128];   // x_t tile, f16, swizzled

    const int tid  = threadIdx.x;          // 0..511
    const int lane = tid & 63;
    const int wid8 = tid >> 6;             // 0..7
    const int w    = wid8 & 3;             // tau / unit group (as v5 wid)
    const int rsel = wid8 >> 2;            // row-slot this wave owns (0/1)
    const int nl = lane & 15, qd = lane >> 4;
    const int n7 = nl & 7;
    const bool lo8 = (nl & 8) == 0;

    // ---------------- weights into VGPRs (per-wave slices) ----------------
    h8_t bw1[2][4], bh1[2];
    #pragma unroll
    for (int j = 0; j < 2; ++j) {
        int G = 8 * w + n7 + 32 * ((nl >> 3) + 2 * j);
        #pragma unroll
        for (int kc = 0; kc < 4; ++kc)
            bw1[j][kc] = load8f_h(w_ih1 + G * 128 + kc * 32 + qd * 8);
        bh1[j] = load8f_h(w_hh1 + G * 32 + qd * 8);
    }
    h8_t bw2[2] = {zero8h(), zero8h()}, bh2[2] = {zero8h(), zero8h()};
    float bs2[4] = {0.f, 0.f, 0.f, 0.f};
    if (w < 2) {
        #pragma unroll
        for (int j = 0; j < 2; ++j) {
            int G = 32 * j + 16 * (nl >> 3) + 8 * w + n7;
            bw2[j] = load8f_h(w_ih2 + G * 32 + qd * 8);
            bh2[j] = (qd < 2) ? load8f_h(w_hh2 + G * 16 + qd * 8) : zero8h();
        }
        int u2 = 8 * w + n7;
        #pragma unroll
        for (int g = 0; g < 4; ++g) bs2[g] = b_ih2[16 * g + u2] + b_hh2[16 * g + u2];
    }
    h8_t b3c[2] = {zero8h(), zero8h()};
    float bs3[4] = {0.f, 0.f, 0.f, 0.f};
    if (wid8 == 2 || wid8 == 3) {
        #pragma unroll
        for (int j = 0; j < 2; ++j) {
            int G = 16 * j + 8 * (nl >> 3) + n7;
            b3c[j] = (qd < 2) ? load8f_h(w_ih3 + G * 16 + qd * 8)
                   : (qd == 2) ? load8f_h(w_hh3 + G * 8) : zero8h();
        }
        #pragma unroll
        for (int g = 0; g < 4; ++g) bs3[g] = b_ih3[8 * g + n7] + b_hh3[8 * g + n7];
    }
    float bs1[4];
    {
        int u1 = 8 * w + n7;
        #pragma unroll
        for (int g = 0; g < 4; ++g) bs1[g] = b_ih1[32 * g + u1] + b_hh1[32 * g + u1];
    }

    // zero both parities of all h-state LDS
    for (int i = tid; i < 2 * 16 * 40; i += 512) (&h1s[0][0][0])[i] = (_Float16)0.f;
    for (int i = tid; i < 2 * 16 * 24; i += 512) (&h2s[0][0][0])[i] = (_Float16)0.f;
    for (int i = tid; i < 2 * 16 * 8;  i += 512) (&h3s[0][0][0])[i] = (_Float16)0.f;

    float c1 = 0.f;     // L1 cell, row-slot rsel
    float c2 = 0.f;     // L2 cell (waves w<2)
    float c3 = 0.f;     // L3 cell (waves 2,3)

    const int b0 = blockIdx.x * 16;

    // ---------------- cooperative x staging (512 threads, 16B load / 8B write) ----
    // thread -> (row = tid>>5, 16B chunk c = (tid>>1)&15, 8B half h = tid&1).
    // LDS layout: row*128 halves + swizzled-chunk*8 + h*4, swz chunk = c ^ (row&7).
    const int xrow = tid >> 5, xch = (tid >> 1) & 15, xh = tid & 1;
    const float* xg = x + ((size_t)(b0 + xrow) * T_LEN) * D_IN + xch * 8 + xh * 4;
    const int xws = (xrow * 16 + (xch ^ (xrow & 7))) * 8 + xh * 4;

    f4_t xa = *(const f4_t*)xg;                        // x_0
    *(h4_t*)&xs[0][xws] = cvt4(xa);
    xa = *(const f4_t*)(xg + D_IN);                    // x_1 -> regs
    __syncthreads();

    // ---------------- one pipelined iteration ----------------
    auto step = [&](auto d1c, auto d2c, auto d3c, auto pc, int t) {
        constexpr bool DO1 = decltype(d1c)::value;
        constexpr bool DO2 = decltype(d2c)::value;
        constexpr bool DO3 = decltype(d3c)::value;
        constexpr int  P   = decltype(pc)::value;

        h8_t a1p = zero8h();
        if constexpr (DO1 || DO2)
            a1p = *(const h8_t*)&h1s[1 - P][nl][qd * 8];             // h1[t-1]

        if constexpr (DO1) {
            h8_t af[4];
            #pragma unroll
            for (int kc = 0; kc < 4; ++kc)
                af[kc] = *(const h8_t*)&xs[P][(nl * 16 + ((4 * kc + qd) ^ n7)) * 8];

            // stage x_{t+1} (in regs) -> xs[1-P]; prefetch x_{t+2} -> regs
            h4_t xcur = cvt4(xa);
            {
                int tn = (t + 2 < T_LEN) ? (t + 2) : (T_LEN - 1);
                xa = *(const f4_t*)(xg + tn * D_IN);
            }
            *(h4_t*)&xs[1 - P][xws] = xcur;

            f4_t acc[2];
            #pragma unroll
            for (int j = 0; j < 2; ++j) {
                f4_t a_ = {0.f, 0.f, 0.f, 0.f};
                #pragma unroll
                for (int kc = 0; kc < 4; ++kc)
                    a_ = __builtin_amdgcn_mfma_f32_16x16x32_f16(af[kc], bw1[j][kc], a_, 0, 0, 0);
                a_ = __builtin_amdgcn_mfma_f32_16x16x32_f16(a1p, bh1[j], a_, 0, 0, 0);
                acc[j] = a_;
            }
            // acc[0]: lo=i / hi=f ; acc[1]: lo=g / hi=o. This wave: row-slot rsel.
            auto ew1 = [&](auto rrc) {
                constexpr int rr = decltype(rrc)::value;
                float s0 = lo8 ? acc[0][rr + 2] : acc[0][rr];
                float s1 = lo8 ? acc[1][rr + 2] : acc[1][rr];
                float x0 = __shfl_xor(s0, 8, 64);
                float x1 = __shfl_xor(s1, 8, 64);
                float vi = lo8 ? acc[0][rr] : x0;
                float vf = lo8 ? x0 : acc[0][rr + 2];
                float vg = lo8 ? acc[1][rr] : x1;
                float vo = lo8 ? x1 : acc[1][rr + 2];
                float ig = sig_(vi + bs1[0]);
                float fg = sig_(vf + bs1[1]);
                float gg = tanh_(vg + bs1[2]);
                float og = sig_(vo + bs1[3]);
                float c = fg * c1 + ig * gg; c1 = c;
                float h = og * tanh_(c);
                h1s[P][4 * qd + rr + (lo8 ? 0 : 2)][8 * w + n7] = (_Float16)h;  // h1[t]
            };
            if (rsel == 0) ew1(std::integral_constant<int, 0>{});
            else           ew1(std::integral_constant<int, 1>{});
        }

        if constexpr (DO2) {
            if (w < 2) {
                h8_t a2p = zero8h();
                if (qd < 2) a2p = *(const h8_t*)&h2s[P][nl][qd * 8]; // h2[t-2]
                f4_t acc2[2];
                #pragma unroll
                for (int j = 0; j < 2; ++j) {
                    f4_t a_ = {0.f, 0.f, 0.f, 0.f};
                    a_ = __builtin_amdgcn_mfma_f32_16x16x32_f16(a1p, bw2[j], a_, 0, 0, 0);
                    a_ = __builtin_amdgcn_mfma_f32_16x16x32_f16(a2p, bh2[j], a_, 0, 0, 0);
                    acc2[j] = a_;
                }
                auto ew2 = [&](auto rrc) {
                    constexpr int rr = decltype(rrc)::value;
                    float s0 = lo8 ? acc2[0][rr + 2] : acc2[0][rr];
                    float s1 = lo8 ? acc2[1][rr + 2] : acc2[1][rr];
                    float x0 = __shfl_xor(s0, 8, 64);
                    float x1 = __shfl_xor(s1, 8, 64);
                    float vi = lo8 ? acc2[0][rr] : x0;
                    float vf = lo8 ? x0 : acc2[0][rr + 2];
                    float vg = lo8 ? acc2[1][rr] : x1;
                    float vo = lo8 ? x1 : acc2[1][rr + 2];
                    float ig = sig_(vi + bs2[0]);
                    float fg = sig_(vf + bs2[1]);
                    float gg = tanh_(vg + bs2[2]);
                    float og = sig_(vo + bs2[3]);
                    float c = fg * c2 + ig * gg; c2 = c;
                    float h = og * tanh_(c);
                    h2s[1 - P][4 * qd + rr + (lo8 ? 0 : 2)][8 * w + n7] = (_Float16)h; // h2[t-1]
                };
                if (rsel == 0) ew2(std::integral_constant<int, 0>{});
                else           ew2(std::integral_constant<int, 1>{});
            }
        }

        if constexpr (DO3) {
            if (wid8 == 2 || wid8 == 3) {
                h8_t a3 = zero8h();
                if (qd < 2)       a3 = *(const h8_t*)&h2s[P][nl][qd * 8];  // h2[t-2]
                else if (qd == 2) a3 = *(const h8_t*)&h3s[1 - P][nl][0];   // h3[t-3]
                f4_t acc3[2];
                #pragma unroll
                for (int j = 0; j < 2; ++j) {
                    f4_t a_ = {0.f, 0.f, 0.f, 0.f};
                    acc3[j] = __builtin_amdgcn_mfma_f32_16x16x32_f16(a3, b3c[j], a_, 0, 0, 0);
                }
                auto l3c = [&](auto rpc) {
                    constexpr int rp = decltype(rpc)::value;
                    float eLo = acc3[0][rp], eHi = acc3[0][rp + 2];
                    float oLo = acc3[1][rp], oHi = acc3[1][rp + 2];
                    float se = lo8 ? eHi : eLo; float xe = __shfl_xor(se, 8, 64);
                    float so = lo8 ? oHi : oLo; float xo = __shfl_xor(so, 8, 64);
                    float vi = lo8 ? eLo : xe;
                    float vf = lo8 ? xe  : eHi;
                    float vg = lo8 ? oLo : xo;
                    float vo = lo8 ? xo  : oHi;
                    float ig = sig_(vi + bs3[0]);
                    float fg = sig_(vf + bs3[1]);
                    float gg = tanh_(vg + bs3[2]);
                    float og = sig_(vo + bs3[3]);
                    float c = fg * c3 + ig * gg; c3 = c;
                    float h = og * tanh_(c);
                    h3s[P][4 * qd + rp + (lo8 ? 0 : 2)][n7] = (_Float16)h;  // h3[t-2]
                };
                if (wid8 == 2) l3c(std::integral_constant<int, 0>{});
                else           l3c(std::integral_constant<int, 1>{});
            }
        }

        bar_lds();
    };

    using TT = std::integral_constant<bool, true>;
    using FF = std::integral_constant<bool, false>;
    using P0 = std::integral_constant<int, 0>;
    using P1 = std::integral_constant<int, 1>;

    // warm-up
    step(TT{}, FF{}, FF{}, P0{}, 0);
    step(TT{}, TT{}, FF{}, P1{}, 1);
    // main: t = 2..63, parity static via x2 unroll
    for (int tb = 1; tb < 32; ++tb) {
        step(TT{}, TT{}, TT{}, P0{}, 2 * tb);
        step(TT{}, TT{}, TT{}, P1{}, 2 * tb + 1);
    }
    // drain
    step(FF{}, TT{}, TT{}, P0{}, 64);
    step(FF{}, FF{}, TT{}, P1{}, 65);

    // ---------------- FC head: h3[63] is in h3s[1] ----------------
    if (tid < 16) {
        float a = fc_b[0];
        #pragma unroll
        for (int u = 0; u < 8; ++u)
            a += fc_w[u] * (float)h3s[1][tid][u];
        out[b0 + tid] = a;
    }
}

extern "C" void kernel_launch(void* const* d_in, const int* in_sizes, int n_in,
                              void* d_out, int out_size, void* d_ws, size_t ws_size,
                              hipStream_t stream) {
    (void)in_sizes; (void)n_in; (void)out_size; (void)d_ws; (void)ws_size;
    const float* x     = (const float*)d_in[0];
    const float* w_ih1 = (const float*)d_in[1];
    const float* w_hh1 = (const float*)d_in[2];
    const float* b_ih1 = (const float*)d_in[3];
    const float* b_hh1 = (const float*)d_in[4];
    const float* w_ih2 = (const float*)d_in[5];
    const float* w_hh2 = (const float*)d_in[6];
    const float* b_ih2 = (const float*)d_in[7];
    const float* b_hh2 = (const float*)d_in[8];
    const float* w_ih3 = (const float*)d_in[9];
    const float* w_hh3 = (const float*)d_in[10];
    const float* b_ih3 = (const float*)d_in[11];
    const float* b_hh3 = (const float*)d_in[12];
    const float* fc_w  = (const float*)d_in[13];
    const float* fc_b  = (const float*)d_in[14];

    dim3 grid(512), block(512);
    hipLaunchKernelGGL(lstm_one, grid, block, 0, stream,
                       x, w_ih1, w_hh1, b_ih1, b_hh1,
                       w_ih2, w_hh2, b_ih2, b_hh2,
                       w_ih3, w_hh3, b_ih3, b_hh3,
                       fc_w, fc_b, (float*)d_out);
}

// Round 4
// 454.588 us; speedup vs baseline: 1.0074x; 1.0074x over previous
//
#include <hip/hip_runtime.h>
#include <cstddef>
#include <type_traits>

// MediumLSTM v7: v6.1 row-split structure with the spill fixed.
// v6.1 post-mortem: __launch_bounds__(512,4) acts with CUDA semantics here
// (min BLOCKS/CU) -> 4 blocks * 8 waves / 4 EU = 8 waves/EU -> VGPR cap 64.
// Demand is ~85 (weights in VGPRs) -> compiler spilled to scratch: WRITE_SIZE
// 32KB -> 31.6MB, FETCH +35MB, and every step's barrier serialized the spill
// reload latency across all 8 waves => 190us/dispatch (worse than v5's 165).
// Fix: (512,2) -> 2 blocks/CU -> 4 waves/EU -> cap 128. Plus register-demand
// trim: wave-disjoint register sets merged (bw2/bh2 with b3c -> bwX/bhX,
// bs2/bs3 -> bsX, c2/c3 -> cX) since allocation is uniform across waves.
//
// Work map per step (wid8 = tid>>6, w = wid8&3, rsel = wid8>>2):
//   L1: all waves, tau-pair w (10 MFMA), elementwise rr=rsel       (1 cell/lane)
//   L2: waves w<2 (wid8 0,1,4,5), unit-group w, rr=rsel            (1 cell/lane)
//   L3: waves wid8==2,3 only, rp=wid8-2                            (1 cell/lane)
// Parity map (P = t&1):
//   L1: reads h1s[1-P], xs[P];  writes h1s[P]    (h1[t])
//   L2: reads h1s[1-P], h2s[P]; writes h2s[1-P]  (h2[t-1])
//   L3: reads h2s[P], h3s[1-P]; writes h3s[P]    (h3[t-2])
//   FC: h3[63] lands in h3s[1] (iter 65).

typedef _Float16 h8_t  __attribute__((ext_vector_type(8)));
typedef _Float16 h4_t  __attribute__((ext_vector_type(4)));
typedef __fp16   p2_t  __attribute__((ext_vector_type(2)));
typedef float    f4_t  __attribute__((ext_vector_type(4)));

#define T_LEN 64
#define D_IN  128

__device__ __forceinline__ float sig_(float x)  { return 1.0f / (1.0f + __expf(-x)); }
__device__ __forceinline__ float tanh_(float x) { float e = __expf(2.0f * x); return 1.0f - 2.0f / (e + 1.0f); }

__device__ __forceinline__ h8_t zero8h() {
    h8_t r = { (_Float16)0.f,(_Float16)0.f,(_Float16)0.f,(_Float16)0.f,
               (_Float16)0.f,(_Float16)0.f,(_Float16)0.f,(_Float16)0.f };
    return r;
}
__device__ __forceinline__ h8_t cvt8(f4_t lo, f4_t hi) {
    union { h8_t v8; p2_t v2[4]; } u;
    u.v2[0] = __builtin_amdgcn_cvt_pkrtz(lo[0], lo[1]);
    u.v2[1] = __builtin_amdgcn_cvt_pkrtz(lo[2], lo[3]);
    u.v2[2] = __builtin_amdgcn_cvt_pkrtz(hi[0], hi[1]);
    u.v2[3] = __builtin_amdgcn_cvt_pkrtz(hi[2], hi[3]);
    return u.v8;
}
__device__ __forceinline__ h4_t cvt4(f4_t v) {
    union { h4_t v4; p2_t v2[2]; } u;
    u.v2[0] = __builtin_amdgcn_cvt_pkrtz(v[0], v[1]);
    u.v2[1] = __builtin_amdgcn_cvt_pkrtz(v[2], v[3]);
    return u.v4;
}
__device__ __forceinline__ h8_t load8f_h(const float* __restrict__ p) {
    f4_t lo = *(const f4_t*)p, hi = *(const f4_t*)(p + 4);
    return cvt8(lo, hi);
}

// lgkm-only barrier: LDS writes committed (lgkmcnt=0) before the convergent
// barrier; x-prefetch (vmcnt) stays in flight, HW-enforced at register use.
__device__ __forceinline__ void bar_lds() {
    asm volatile("s_waitcnt lgkmcnt(0)" ::: "memory");
    __builtin_amdgcn_s_barrier();
}

__global__ __launch_bounds__(512, 2)
void lstm_one(const float* __restrict__ x,
              const float* __restrict__ w_ih1, const float* __restrict__ w_hh1,
              const float* __restrict__ b_ih1, const float* __restrict__ b_hh1,
              const float* __restrict__ w_ih2, const float* __restrict__ w_hh2,
              const float* __restrict__ b_ih2, const float* __restrict__ b_hh2,
              const float* __restrict__ w_ih3, const float* __restrict__ w_hh3,
              const float* __restrict__ b_ih3, const float* __restrict__ b_hh3,
              const float* __restrict__ fc_w, const float* __restrict__ fc_b,
              float* __restrict__ out)
{
    __shared__ __align__(16) _Float16 h1s[2][16][40];
    __shared__ __align__(16) _Float16 h2s[2][16][24];
    __shared__ __align__(16) _Float16 h3s[2][16][8];
    __shared__ __align__(16) _Float16 xs[2][16 * 128];   // x_t tile, f16, swizzled

    const int tid  = threadIdx.x;          // 0..511
    const int lane = tid & 63;
    const int wid8 = tid >> 6;             // 0..7
    const int w    = wid8 & 3;             // tau / unit group
    const int rsel = wid8 >> 2;            // row-slot this wave owns (0/1)
    const int nl = lane & 15, qd = lane >> 4;
    const int n7 = nl & 7;
    const bool lo8 = (nl & 8) == 0;

    // ---------------- weights into VGPRs (per-wave slices) ----------------
    h8_t bw1[2][4], bh1[2];
    #pragma unroll
    for (int j = 0; j < 2; ++j) {
        int G = 8 * w + n7 + 32 * ((nl >> 3) + 2 * j);
        #pragma unroll
        for (int kc = 0; kc < 4; ++kc)
            bw1[j][kc] = load8f_h(w_ih1 + G * 128 + kc * 32 + qd * 8);
        bh1[j] = load8f_h(w_hh1 + G * 32 + qd * 8);
    }
    // Merged L2/L3 register set (wave-disjoint ownership):
    //   waves with w<2 (wid8 0,1,4,5): bwX/bhX = L2 w_ih/w_hh slices, bsX = L2 bias
    //   waves wid8 2,3:                bwX = L3 combined slice,       bsX = L3 bias
    //   waves 6,7: unused (zero)
    h8_t bwX[2] = {zero8h(), zero8h()}, bhX[2] = {zero8h(), zero8h()};
    float bsX[4] = {0.f, 0.f, 0.f, 0.f};
    if (w < 2) {
        #pragma unroll
        for (int j = 0; j < 2; ++j) {
            int G = 32 * j + 16 * (nl >> 3) + 8 * w + n7;
            bwX[j] = load8f_h(w_ih2 + G * 32 + qd * 8);
            bhX[j] = (qd < 2) ? load8f_h(w_hh2 + G * 16 + qd * 8) : zero8h();
        }
        int u2 = 8 * w + n7;
        #pragma unroll
        for (int g = 0; g < 4; ++g) bsX[g] = b_ih2[16 * g + u2] + b_hh2[16 * g + u2];
    } else if (wid8 == 2 || wid8 == 3) {
        #pragma unroll
        for (int j = 0; j < 2; ++j) {
            int G = 16 * j + 8 * (nl >> 3) + n7;
            bwX[j] = (qd < 2) ? load8f_h(w_ih3 + G * 16 + qd * 8)
                   : (qd == 2) ? load8f_h(w_hh3 + G * 8) : zero8h();
        }
        #pragma unroll
        for (int g = 0; g < 4; ++g) bsX[g] = b_ih3[8 * g + n7] + b_hh3[8 * g + n7];
    }
    float bs1[4];
    {
        int u1 = 8 * w + n7;
        #pragma unroll
        for (int g = 0; g < 4; ++g) bs1[g] = b_ih1[32 * g + u1] + b_hh1[32 * g + u1];
    }

    // zero both parities of all h-state LDS
    for (int i = tid; i < 2 * 16 * 40; i += 512) (&h1s[0][0][0])[i] = (_Float16)0.f;
    for (int i = tid; i < 2 * 16 * 24; i += 512) (&h2s[0][0][0])[i] = (_Float16)0.f;
    for (int i = tid; i < 2 * 16 * 8;  i += 512) (&h3s[0][0][0])[i] = (_Float16)0.f;

    float c1 = 0.f;     // L1 cell, row-slot rsel
    float cX = 0.f;     // L2 cell (waves w<2) / L3 cell (waves 2,3) - disjoint

    const int b0 = blockIdx.x * 16;

    // ---------------- cooperative x staging (512 threads, 16B load / 8B write) ----
    // thread -> (row = tid>>5, 16B chunk c = (tid>>1)&15, 8B half h = tid&1).
    // LDS layout: row*128 halves + swizzled-chunk*8 + h*4, swz chunk = c ^ (row&7).
    const int xrow = tid >> 5, xch = (tid >> 1) & 15, xh = tid & 1;
    const float* xg = x + ((size_t)(b0 + xrow) * T_LEN) * D_IN + xch * 8 + xh * 4;
    const int xws = (xrow * 16 + (xch ^ (xrow & 7))) * 8 + xh * 4;

    f4_t xa = *(const f4_t*)xg;                        // x_0
    *(h4_t*)&xs[0][xws] = cvt4(xa);
    xa = *(const f4_t*)(xg + D_IN);                    // x_1 -> regs
    __syncthreads();

    // ---------------- one pipelined iteration ----------------
    auto step = [&](auto d1c, auto d2c, auto d3c, auto pc, int t) {
        constexpr bool DO1 = decltype(d1c)::value;
        constexpr bool DO2 = decltype(d2c)::value;
        constexpr bool DO3 = decltype(d3c)::value;
        constexpr int  P   = decltype(pc)::value;

        h8_t a1p = zero8h();
        if constexpr (DO1 || DO2)
            a1p = *(const h8_t*)&h1s[1 - P][nl][qd * 8];             // h1[t-1]

        if constexpr (DO1) {
            h8_t af[4];
            #pragma unroll
            for (int kc = 0; kc < 4; ++kc)
                af[kc] = *(const h8_t*)&xs[P][(nl * 16 + ((4 * kc + qd) ^ n7)) * 8];

            // stage x_{t+1} (in regs) -> xs[1-P]; prefetch x_{t+2} -> regs
            h4_t xcur = cvt4(xa);
            {
                int tn = (t + 2 < T_LEN) ? (t + 2) : (T_LEN - 1);
                xa = *(const f4_t*)(xg + tn * D_IN);
            }
            *(h4_t*)&xs[1 - P][xws] = xcur;

            f4_t acc[2];
            #pragma unroll
            for (int j = 0; j < 2; ++j) {
                f4_t a_ = {0.f, 0.f, 0.f, 0.f};
                #pragma unroll
                for (int kc = 0; kc < 4; ++kc)
                    a_ = __builtin_amdgcn_mfma_f32_16x16x32_f16(af[kc], bw1[j][kc], a_, 0, 0, 0);
                a_ = __builtin_amdgcn_mfma_f32_16x16x32_f16(a1p, bh1[j], a_, 0, 0, 0);
                acc[j] = a_;
            }
            // acc[0]: lo=i / hi=f ; acc[1]: lo=g / hi=o. This wave: row-slot rsel.
            auto ew1 = [&](auto rrc) {
                constexpr int rr = decltype(rrc)::value;
                float s0 = lo8 ? acc[0][rr + 2] : acc[0][rr];
                float s1 = lo8 ? acc[1][rr + 2] : acc[1][rr];
                float x0 = __shfl_xor(s0, 8, 64);
                float x1 = __shfl_xor(s1, 8, 64);
                float vi = lo8 ? acc[0][rr] : x0;
                float vf = lo8 ? x0 : acc[0][rr + 2];
                float vg = lo8 ? acc[1][rr] : x1;
                float vo = lo8 ? x1 : acc[1][rr + 2];
                float ig = sig_(vi + bs1[0]);
                float fg = sig_(vf + bs1[1]);
                float gg = tanh_(vg + bs1[2]);
                float og = sig_(vo + bs1[3]);
                float c = fg * c1 + ig * gg; c1 = c;
                float h = og * tanh_(c);
                h1s[P][4 * qd + rr + (lo8 ? 0 : 2)][8 * w + n7] = (_Float16)h;  // h1[t]
            };
            if (rsel == 0) ew1(std::integral_constant<int, 0>{});
            else           ew1(std::integral_constant<int, 1>{});
        }

        if constexpr (DO2) {
            if (w < 2) {
                h8_t a2p = zero8h();
                if (qd < 2) a2p = *(const h8_t*)&h2s[P][nl][qd * 8]; // h2[t-2]
                f4_t acc2[2];
                #pragma unroll
                for (int j = 0; j < 2; ++j) {
                    f4_t a_ = {0.f, 0.f, 0.f, 0.f};
                    a_ = __builtin_amdgcn_mfma_f32_16x16x32_f16(a1p, bwX[j], a_, 0, 0, 0);
                    a_ = __builtin_amdgcn_mfma_f32_16x16x32_f16(a2p, bhX[j], a_, 0, 0, 0);
                    acc2[j] = a_;
                }
                auto ew2 = [&](auto rrc) {
                    constexpr int rr = decltype(rrc)::value;
                    float s0 = lo8 ? acc2[0][rr + 2] : acc2[0][rr];
                    float s1 = lo8 ? acc2[1][rr + 2] : acc2[1][rr];
                    float x0 = __shfl_xor(s0, 8, 64);
                    float x1 = __shfl_xor(s1, 8, 64);
                    float vi = lo8 ? acc2[0][rr] : x0;
                    float vf = lo8 ? x0 : acc2[0][rr + 2];
                    float vg = lo8 ? acc2[1][rr] : x1;
                    float vo = lo8 ? x1 : acc2[1][rr + 2];
                    float ig = sig_(vi + bsX[0]);
                    float fg = sig_(vf + bsX[1]);
                    float gg = tanh_(vg + bsX[2]);
                    float og = sig_(vo + bsX[3]);
                    float c = fg * cX + ig * gg; cX = c;
                    float h = og * tanh_(c);
                    h2s[1 - P][4 * qd + rr + (lo8 ? 0 : 2)][8 * w + n7] = (_Float16)h; // h2[t-1]
                };
                if (rsel == 0) ew2(std::integral_constant<int, 0>{});
                else           ew2(std::integral_constant<int, 1>{});
            }
        }

        if constexpr (DO3) {
            if (wid8 == 2 || wid8 == 3) {
                h8_t a3 = zero8h();
                if (qd < 2)       a3 = *(const h8_t*)&h2s[P][nl][qd * 8];  // h2[t-2]
                else if (qd == 2) a3 = *(const h8_t*)&h3s[1 - P][nl][0];   // h3[t-3]
                f4_t acc3[2];
                #pragma unroll
                for (int j = 0; j < 2; ++j) {
                    f4_t a_ = {0.f, 0.f, 0.f, 0.f};
                    acc3[j] = __builtin_amdgcn_mfma_f32_16x16x32_f16(a3, bwX[j], a_, 0, 0, 0);
                }
                auto l3c = [&](auto rpc) {
                    constexpr int rp = decltype(rpc)::value;
                    float eLo = acc3[0][rp], eHi = acc3[0][rp + 2];
                    float oLo = acc3[1][rp], oHi = acc3[1][rp + 2];
                    float se = lo8 ? eHi : eLo; float xe = __shfl_xor(se, 8, 64);
                    float so = lo8 ? oHi : oLo; float xo = __shfl_xor(so, 8, 64);
                    float vi = lo8 ? eLo : xe;
                    float vf = lo8 ? xe  : eHi;
                    float vg = lo8 ? oLo : xo;
                    float vo = lo8 ? xo  : oHi;
                    float ig = sig_(vi + bsX[0]);
                    float fg = sig_(vf + bsX[1]);
                    float gg = tanh_(vg + bsX[2]);
                    float og = sig_(vo + bsX[3]);
                    float c = fg * cX + ig * gg; cX = c;
                    float h = og * tanh_(c);
                    h3s[P][4 * qd + rp + (lo8 ? 0 : 2)][n7] = (_Float16)h;  // h3[t-2]
                };
                if (wid8 == 2) l3c(std::integral_constant<int, 0>{});
                else           l3c(std::integral_constant<int, 1>{});
            }
        }

        bar_lds();
    };

    using TT = std::integral_constant<bool, true>;
    using FF = std::integral_constant<bool, false>;
    using P0 = std::integral_constant<int, 0>;
    using P1 = std::integral_constant<int, 1>;

    // warm-up
    step(TT{}, FF{}, FF{}, P0{}, 0);
    step(TT{}, TT{}, FF{}, P1{}, 1);
    // main: t = 2..63, parity static via x2 unroll
    for (int tb = 1; tb < 32; ++tb) {
        step(TT{}, TT{}, TT{}, P0{}, 2 * tb);
        step(TT{}, TT{}, TT{}, P1{}, 2 * tb + 1);
    }
    // drain
    step(FF{}, TT{}, TT{}, P0{}, 64);
    step(FF{}, FF{}, TT{}, P1{}, 65);

    // ---------------- FC head: h3[63] is in h3s[1] ----------------
    if (tid < 16) {
        float a = fc_b[0];
        #pragma unroll
        for (int u = 0; u < 8; ++u)
            a += fc_w[u] * (float)h3s[1][tid][u];
        out[b0 + tid] = a;
    }
}

extern "C" void kernel_launch(void* const* d_in, const int* in_sizes, int n_in,
                              void* d_out, int out_size, void* d_ws, size_t ws_size,
                              hipStream_t stream) {
    (void)in_sizes; (void)n_in; (void)out_size; (void)d_ws; (void)ws_size;
    const float* x     = (const float*)d_in[0];
    const float* w_ih1 = (const float*)d_in[1];
    const float* w_hh1 = (const float*)d_in[2];
    const float* b_ih1 = (const float*)d_in[3];
    const float* b_hh1 = (const float*)d_in[4];
    const float* w_ih2 = (const float*)d_in[5];
    const float* w_hh2 = (const float*)d_in[6];
    const float* b_ih2 = (const float*)d_in[7];
    const float* b_hh2 = (const float*)d_in[8];
    const float* w_ih3 = (const float*)d_in[9];
    const float* w_hh3 = (const float*)d_in[10];
    const float* b_ih3 = (const float*)d_in[11];
    const float* b_hh3 = (const float*)d_in[12];
    const float* fc_w  = (const float*)d_in[13];
    const float* fc_b  = (const float*)d_in[14];

    dim3 grid(512), block(512);
    hipLaunchKernelGGL(lstm_one, grid, block, 0, stream,
                       x, w_ih1, w_hh1, b_ih1, b_hh1,
                       w_ih2, w_hh2, b_ih2, b_hh2,
                       w_ih3, w_hh3, b_ih3, b_hh3,
                       fc_w, fc_b, (float*)d_out);
}

// Round 5
// 391.033 us; speedup vs baseline: 1.1711x; 1.1625x over previous
//
#include <hip/hip_runtime.h>
#include <cstddef>
#include <type_traits>

// MediumLSTM v8: v5 structure (the measured best: 512 blocks x 4 waves, tau-pair
// per wave) + three issue-cut levers, after v6/v7 refuted the "more waves" path:
// v7 showed extra waves beyond the natural 2048-wave decomposition duplicate
// fragment-load/VALU work (+27% per-SIMD busy time) while effective residency
// stays ~2 waves/SIMD. So: keep v5's decomposition, cut the per-cell issue.
//  (a) raw v_rcp_f32 instead of IEEE 1/x (5 div/cell were div_scale+div_fmas+
//      div_fixup sequences without fast-math),
//  (b) shared-rcp gate algebra: i*g and o*tanh(c) each fuse into one reciprocal
//      => 5 exp + 3 rcp per cell (was 5 exp + 5 div); 2c clamped to +-30 so the
//      fused tanh(c) form cannot reach inf*0 (exact past tanh saturation),
//  (c) lgkm-only barrier (no per-step vmcnt drain; x-prefetch is register-
//      consumed so the HW waitcnt at use covers it) - validated in v6.1/v7.
//
// Work map per step (wid = tid>>6, 0..3):
//   L1: all waves, tau-pair wid (10 MFMA), 2 cells/lane
//   L2: waves 0,1, unit-group wid, 2 cells/lane
//   L3: waves 2,3, row-pair wid-2, 1 cell/lane
// Parity map (P = t&1):
//   L1: reads h1s[1-P], xs[P];  writes h1s[P]    (h1[t])
//   L2: reads h1s[1-P], h2s[P]; writes h2s[1-P]  (h2[t-1])
//   L3: reads h2s[P], h3s[1-P]; writes h3s[P]    (h3[t-2])
//   FC: h3[63] lands in h3s[1] (iter 65).

typedef _Float16 h8_t  __attribute__((ext_vector_type(8)));
typedef __fp16   p2_t  __attribute__((ext_vector_type(2)));
typedef float    f4_t  __attribute__((ext_vector_type(4)));

#define T_LEN 64
#define D_IN  128

__device__ __forceinline__ float rcp_(float x) { return __builtin_amdgcn_rcpf(x); }

// Full LSTM cell epilogue with shared reciprocals.
//   i*g = (e2g-1) * rcp((1+e^-vi)(e2g+1));  f = rcp(1+e^-vf)
//   h   = o*tanh(c) = (e2c-1) * rcp((1+e^-vo)(e2c+1)), 2c clamped to +-30
__device__ __forceinline__ float cell_(float vi, float vf, float vg, float vo,
                                       float& c) {
    float eni = __expf(-vi);
    float enf = __expf(-vf);
    float eno = __expf(-vo);
    float e2g = __expf(2.0f * vg);
    float igg = (e2g - 1.0f) * rcp_((1.0f + eni) * (e2g + 1.0f));
    c = rcp_(1.0f + enf) * c + igg;
    float t2 = fminf(fmaxf(2.0f * c, -30.0f), 30.0f);
    float e2c = __expf(t2);
    return (e2c - 1.0f) * rcp_((1.0f + eno) * (e2c + 1.0f));
}

__device__ __forceinline__ h8_t zero8h() {
    h8_t r = { (_Float16)0.f,(_Float16)0.f,(_Float16)0.f,(_Float16)0.f,
               (_Float16)0.f,(_Float16)0.f,(_Float16)0.f,(_Float16)0.f };
    return r;
}
__device__ __forceinline__ h8_t cvt8(f4_t lo, f4_t hi) {
    union { h8_t v8; p2_t v2[4]; } u;
    u.v2[0] = __builtin_amdgcn_cvt_pkrtz(lo[0], lo[1]);
    u.v2[1] = __builtin_amdgcn_cvt_pkrtz(lo[2], lo[3]);
    u.v2[2] = __builtin_amdgcn_cvt_pkrtz(hi[0], hi[1]);
    u.v2[3] = __builtin_amdgcn_cvt_pkrtz(hi[2], hi[3]);
    return u.v8;
}
__device__ __forceinline__ h8_t load8f_h(const float* __restrict__ p) {
    f4_t lo = *(const f4_t*)p, hi = *(const f4_t*)(p + 4);
    return cvt8(lo, hi);
}

// lgkm-only barrier: LDS writes committed before the convergent barrier; the
// x-prefetch (vmcnt) stays in flight, HW-enforced at register use.
__device__ __forceinline__ void bar_lds() {
    asm volatile("s_waitcnt lgkmcnt(0)" ::: "memory");
    __builtin_amdgcn_s_barrier();
}

__global__ __launch_bounds__(256, 2)
void lstm_one(const float* __restrict__ x,
              const float* __restrict__ w_ih1, const float* __restrict__ w_hh1,
              const float* __restrict__ b_ih1, const float* __restrict__ b_hh1,
              const float* __restrict__ w_ih2, const float* __restrict__ w_hh2,
              const float* __restrict__ b_ih2, const float* __restrict__ b_hh2,
              const float* __restrict__ w_ih3, const float* __restrict__ w_hh3,
              const float* __restrict__ b_ih3, const float* __restrict__ b_hh3,
              const float* __restrict__ fc_w, const float* __restrict__ fc_b,
              float* __restrict__ out)
{
    __shared__ __align__(16) _Float16 h1s[2][16][40];
    __shared__ __align__(16) _Float16 h2s[2][16][24];
    __shared__ __align__(16) _Float16 h3s[2][16][8];
    __shared__ __align__(16) _Float16 xs[2][16 * 128];   // x_t tile, f16, swizzled

    const int tid  = threadIdx.x;          // 0..255
    const int lane = tid & 63;
    const int wid  = tid >> 6;             // 0..3
    const int nl = lane & 15, qd = lane >> 4;
    const int n7 = nl & 7;
    const bool lo8 = (nl & 8) == 0;

    // ---------------- weights into VGPRs (per-wave slices) ----------------
    h8_t bw1[2][4], bh1[2];
    #pragma unroll
    for (int j = 0; j < 2; ++j) {
        int G = 8 * wid + n7 + 32 * ((nl >> 3) + 2 * j);
        #pragma unroll
        for (int kc = 0; kc < 4; ++kc)
            bw1[j][kc] = load8f_h(w_ih1 + G * 128 + kc * 32 + qd * 8);
        bh1[j] = load8f_h(w_hh1 + G * 32 + qd * 8);
    }
    h8_t bw2[2] = {zero8h(), zero8h()}, bh2[2] = {zero8h(), zero8h()};
    float bs2[4] = {0.f, 0.f, 0.f, 0.f};
    if (wid < 2) {
        #pragma unroll
        for (int j = 0; j < 2; ++j) {
            int G = 32 * j + 16 * (nl >> 3) + 8 * wid + n7;
            bw2[j] = load8f_h(w_ih2 + G * 32 + qd * 8);
            bh2[j] = (qd < 2) ? load8f_h(w_hh2 + G * 16 + qd * 8) : zero8h();
        }
        int u2 = 8 * wid + n7;
        #pragma unroll
        for (int g = 0; g < 4; ++g) bs2[g] = b_ih2[16 * g + u2] + b_hh2[16 * g + u2];
    }
    h8_t b3c[2] = {zero8h(), zero8h()};
    float bs3[4] = {0.f, 0.f, 0.f, 0.f};
    if (wid >= 2) {
        #pragma unroll
        for (int j = 0; j < 2; ++j) {
            int G = 16 * j + 8 * (nl >> 3) + n7;
            b3c[j] = (qd < 2) ? load8f_h(w_ih3 + G * 16 + qd * 8)
                   : (qd == 2) ? load8f_h(w_hh3 + G * 8) : zero8h();
        }
        #pragma unroll
        for (int g = 0; g < 4; ++g) bs3[g] = b_ih3[8 * g + n7] + b_hh3[8 * g + n7];
    }
    float bs1[4];
    {
        int u1 = 8 * wid + n7;
        #pragma unroll
        for (int g = 0; g < 4; ++g) bs1[g] = b_ih1[32 * g + u1] + b_hh1[32 * g + u1];
    }

    // zero both parities of all h-state LDS
    for (int i = tid; i < 2 * 16 * 40; i += 256) (&h1s[0][0][0])[i] = (_Float16)0.f;
    for (int i = tid; i < 2 * 16 * 24; i += 256) (&h2s[0][0][0])[i] = (_Float16)0.f;
    for (int i = tid; i < 2 * 16 * 8;  i += 256) (&h3s[0][0][0])[i] = (_Float16)0.f;

    float c1[2] = {0.f, 0.f};   // L1 cells, rows rr (lo8) / rr+2 (hi8)
    float c2[2] = {0.f, 0.f};   // L2 cells (waves 0,1)
    float c3    = 0.f;          // L3 cell  (waves 2,3)

    const int b0 = blockIdx.x * 16;

    // ---------------- cooperative x staging ----------------
    // thread -> (row = tid>>4, 8-float chunk cc = tid&15); 16B LDS granules with
    // XOR swizzle (slot ^= row&7) so fragment reads spread over all 8 bank-quads.
    const int xrow = tid >> 4, xcc = tid & 15;
    const float* xg = x + ((size_t)(b0 + xrow) * T_LEN) * D_IN + xcc * 8;
    const int xws = (xrow * 16 + (xcc ^ (xrow & 7))) * 8;

    f4_t xa0 = *(const f4_t*)xg, xa1 = *(const f4_t*)(xg + 4);      // x_0
    *(h8_t*)&xs[0][xws] = cvt8(xa0, xa1);
    xa0 = *(const f4_t*)(xg + D_IN);                                // x_1 -> regs
    xa1 = *(const f4_t*)(xg + D_IN + 4);
    bar_lds();

    // ---------------- one pipelined iteration ----------------
    auto step = [&](auto d1c, auto d2c, auto d3c, auto pc, int t) {
        constexpr bool DO1 = decltype(d1c)::value;
        constexpr bool DO2 = decltype(d2c)::value;
        constexpr bool DO3 = decltype(d3c)::value;
        constexpr int  P   = decltype(pc)::value;

        h8_t a1p = zero8h();
        if constexpr (DO1 || DO2)
            a1p = *(const h8_t*)&h1s[1 - P][nl][qd * 8];             // h1[t-1]

        if constexpr (DO1) {
            h8_t af[4];
            #pragma unroll
            for (int kc = 0; kc < 4; ++kc)
                af[kc] = *(const h8_t*)&xs[P][(nl * 16 + ((4 * kc + qd) ^ n7)) * 8];

            // stage x_{t+1} (in regs) -> xs[1-P]; prefetch x_{t+2} -> regs
            h8_t xcur = cvt8(xa0, xa1);
            {
                int tn = (t + 2 < T_LEN) ? (t + 2) : (T_LEN - 1);
                const float* xn = xg + (size_t)tn * D_IN;
                xa0 = *(const f4_t*)xn;
                xa1 = *(const f4_t*)(xn + 4);
            }
            *(h8_t*)&xs[1 - P][xws] = xcur;

            f4_t acc[2];
            #pragma unroll
            for (int j = 0; j < 2; ++j) {
                f4_t a_ = {0.f, 0.f, 0.f, 0.f};
                #pragma unroll
                for (int kc = 0; kc < 4; ++kc)
                    a_ = __builtin_amdgcn_mfma_f32_16x16x32_f16(af[kc], bw1[j][kc], a_, 0, 0, 0);
                a_ = __builtin_amdgcn_mfma_f32_16x16x32_f16(a1p, bh1[j], a_, 0, 0, 0);
                acc[j] = a_;
            }
            // acc[0]: lo=i / hi=f ; acc[1]: lo=g / hi=o. One shfl per reg pair.
            #pragma unroll
            for (int rr = 0; rr < 2; ++rr) {
                float s0 = lo8 ? acc[0][rr + 2] : acc[0][rr];
                float s1 = lo8 ? acc[1][rr + 2] : acc[1][rr];
                float x0 = __shfl_xor(s0, 8, 64);
                float x1 = __shfl_xor(s1, 8, 64);
                float vi = lo8 ? acc[0][rr] : x0;
                float vf = lo8 ? x0 : acc[0][rr + 2];
                float vg = lo8 ? acc[1][rr] : x1;
                float vo = lo8 ? x1 : acc[1][rr + 2];
                float h = cell_(vi + bs1[0], vf + bs1[1], vg + bs1[2], vo + bs1[3], c1[rr]);
                h1s[P][4 * qd + rr + (lo8 ? 0 : 2)][8 * wid + n7] = (_Float16)h;  // h1[t]
            }
        }

        if constexpr (DO2) {
            if (wid < 2) {
                h8_t a2p = zero8h();
                if (qd < 2) a2p = *(const h8_t*)&h2s[P][nl][qd * 8]; // h2[t-2]
                f4_t acc2[2];
                #pragma unroll
                for (int j = 0; j < 2; ++j) {
                    f4_t a_ = {0.f, 0.f, 0.f, 0.f};
                    a_ = __builtin_amdgcn_mfma_f32_16x16x32_f16(a1p, bw2[j], a_, 0, 0, 0);
                    a_ = __builtin_amdgcn_mfma_f32_16x16x32_f16(a2p, bh2[j], a_, 0, 0, 0);
                    acc2[j] = a_;
                }
                #pragma unroll
                for (int rr = 0; rr < 2; ++rr) {
                    float s0 = lo8 ? acc2[0][rr + 2] : acc2[0][rr];
                    float s1 = lo8 ? acc2[1][rr + 2] : acc2[1][rr];
                    float x0 = __shfl_xor(s0, 8, 64);
                    float x1 = __shfl_xor(s1, 8, 64);
                    float vi = lo8 ? acc2[0][rr] : x0;
                    float vf = lo8 ? x0 : acc2[0][rr + 2];
                    float vg = lo8 ? acc2[1][rr] : x1;
                    float vo = lo8 ? x1 : acc2[1][rr + 2];
                    float h = cell_(vi + bs2[0], vf + bs2[1], vg + bs2[2], vo + bs2[3], c2[rr]);
                    h2s[1 - P][4 * qd + rr + (lo8 ? 0 : 2)][8 * wid + n7] = (_Float16)h; // h2[t-1]
                }
            }
        }

        if constexpr (DO3) {
            if (wid >= 2) {
                h8_t a3 = zero8h();
                if (qd < 2)       a3 = *(const h8_t*)&h2s[P][nl][qd * 8];  // h2[t-2]
                else if (qd == 2) a3 = *(const h8_t*)&h3s[1 - P][nl][0];   // h3[t-3]
                f4_t acc3[2];
                #pragma unroll
                for (int j = 0; j < 2; ++j) {
                    f4_t a_ = {0.f, 0.f, 0.f, 0.f};
                    acc3[j] = __builtin_amdgcn_mfma_f32_16x16x32_f16(a3, b3c[j], a_, 0, 0, 0);
                }
                auto l3c = [&](auto rpc) {
                    constexpr int rp = decltype(rpc)::value;
                    float eLo = acc3[0][rp],     oLo = acc3[1][rp];
                    float eHi = acc3[0][rp + 2], oHi = acc3[1][rp + 2];
                    float se = lo8 ? eHi : eLo; float xe = __shfl_xor(se, 8, 64);
                    float so = lo8 ? oHi : oLo; float xo = __shfl_xor(so, 8, 64);
                    float vi = lo8 ? eLo : xe;
                    float vf = lo8 ? xe  : eHi;
                    float vg = lo8 ? oLo : xo;
                    float vo = lo8 ? xo  : oHi;
                    float h = cell_(vi + bs3[0], vf + bs3[1], vg + bs3[2], vo + bs3[3], c3);
                    h3s[P][4 * qd + rp + (lo8 ? 0 : 2)][n7] = (_Float16)h;  // h3[t-2]
                };
                if (wid == 2) l3c(std::integral_constant<int, 0>{});
                else          l3c(std::integral_constant<int, 1>{});
            }
        }

        bar_lds();
    };

    using TT = std::integral_constant<bool, true>;
    using FF = std::integral_constant<bool, false>;
    using P0 = std::integral_constant<int, 0>;
    using P1 = std::integral_constant<int, 1>;

    // warm-up
    step(TT{}, FF{}, FF{}, P0{}, 0);
    step(TT{}, TT{}, FF{}, P1{}, 1);
    // main: t = 2..63, parity static via x2 unroll
    for (int tb = 1; tb < 32; ++tb) {
        step(TT{}, TT{}, TT{}, P0{}, 2 * tb);
        step(TT{}, TT{}, TT{}, P1{}, 2 * tb + 1);
    }
    // drain
    step(FF{}, TT{}, TT{}, P0{}, 64);
    step(FF{}, FF{}, TT{}, P1{}, 65);

    // ---------------- FC head: h3[63] is in h3s[1] ----------------
    if (tid < 16) {
        float a = fc_b[0];
        #pragma unroll
        for (int u = 0; u < 8; ++u)
            a += fc_w[u] * (float)h3s[1][tid][u];
        out[b0 + tid] = a;
    }
}

extern "C" void kernel_launch(void* const* d_in, const int* in_sizes, int n_in,
                              void* d_out, int out_size, void* d_ws, size_t ws_size,
                              hipStream_t stream) {
    (void)in_sizes; (void)n_in; (void)out_size; (void)d_ws; (void)ws_size;
    const float* x     = (const float*)d_in[0];
    const float* w_ih1 = (const float*)d_in[1];
    const float* w_hh1 = (const float*)d_in[2];
    const float* b_ih1 = (const float*)d_in[3];
    const float* b_hh1 = (const float*)d_in[4];
    const float* w_ih2 = (const float*)d_in[5];
    const float* w_hh2 = (const float*)d_in[6];
    const float* b_ih2 = (const float*)d_in[7];
    const float* b_hh2 = (const float*)d_in[8];
    const float* w_ih3 = (const float*)d_in[9];
    const float* w_hh3 = (const float*)d_in[10];
    const float* b_ih3 = (const float*)d_in[11];
    const float* b_hh3 = (const float*)d_in[12];
    const float* fc_w  = (const float*)d_in[13];
    const float* fc_b  = (const float*)d_in[14];

    dim3 grid(512), block(256);
    hipLaunchKernelGGL(lstm_one, grid, block, 0, stream,
                       x, w_ih1, w_hh1, b_ih1, b_hh1,
                       w_ih2, w_hh2, b_ih2, b_hh2,
                       w_ih3, w_hh3, b_ih3, b_hh3,
                       fc_w, fc_b, (float*)d_out);
}